// Round 4
// baseline (391.619 us; speedup 1.0000x reference)
//
#include <hip/hip_runtime.h>
#include <hip/hip_cooperative_groups.h>
#include <math.h>

// Problem constants: B=128, N=131072, D=1 (fp32)
#define PF_B 128
#define PF_N 131072
#define TPB 256

// ---- cooperative (fused) config: 512 blocks = 2 blocks/CU needed ----
#define C_NBLK 512
#define C_BPB (C_NBLK / PF_B)                 // 4 blocks per batch
#define C_EPB (PF_N / C_BPB)                  // 32768 elems per block
#define C_ITERS (C_EPB / (TPB * 4))           // 32 float4 iters per thread

// ---- fallback (two-pass) config ----
#define F_EPT 8
#define F_EPB (TPB * F_EPT)                   // 2048
#define F_BPB (PF_N / F_EPB)                  // 64 blocks per batch
#define F_GRID (PF_B * F_BPB)                 // 8192 blocks

namespace cg = cooperative_groups;

typedef float nfloat4 __attribute__((ext_vector_type(4)));  // native vec for builtins

__device__ __forceinline__ void nt_store4(float* p, float4 v) {
    nfloat4 nv; nv.x = v.x; nv.y = v.y; nv.z = v.z; nv.w = v.w;
    __builtin_nontemporal_store(nv, (nfloat4*)p);
}

__device__ __forceinline__ void compute4(const float4 x4, const float4 n4,
                                         const float4 wt4, float ob, float c,
                                         float4* xn_out, float4* wv_out,
                                         float* lsum) {
    const float sq10   = 3.16227770f;
    const float nhl2pi = -0.9189385f;
    float xs[4] = {x4.x, x4.y, x4.z, x4.w};
    float ns[4] = {n4.x, n4.y, n4.z, n4.w};
    float ws[4] = {wt4.x, wt4.y, wt4.z, wt4.w};
    float xn[4], wn[4];
    #pragma unroll
    for (int j = 0; j < 4; ++j) {
        const float x    = xs[j];
        const float mean = x * 0.5f
                         + 25.0f * x * __builtin_amdgcn_rcpf(x * x + 1.0f)
                         + c;
        const float xnew = mean + ns[j] * sq10;
        xn[j] = xnew;
        const float om = (xnew * xnew) * 0.05f;
        const float d  = ob - om;
        const float wv = ws[j] * __expf(-0.5f * d * d + nhl2pi);
        wn[j] = wv;
        *lsum += wv;
    }
    xn_out->x = xn[0]; xn_out->y = xn[1]; xn_out->z = xn[2]; xn_out->w = xn[3];
    wv_out->x = wn[0]; wv_out->y = wn[1]; wv_out->z = wn[2]; wv_out->w = wn[3];
}

__device__ __forceinline__ void block_reduce_atomic(float lsum, float* target,
                                                    float* red) {
    #pragma unroll
    for (int off = 32; off > 0; off >>= 1)
        lsum += __shfl_down(lsum, off, 64);
    if ((threadIdx.x & 63) == 0) red[threadIdx.x >> 6] = lsum;
    __syncthreads();
    if (threadIdx.x == 0) {
        float s = 0.0f;
        #pragma unroll
        for (int i = 0; i < TPB / 64; ++i) s += red[i];
        atomicAdd(target, s);
    }
}

// ======================= cooperative fused kernel =======================
__global__ __launch_bounds__(TPB, 2) void pf_fused(
    const float* __restrict__ particles,
    const float* __restrict__ weights,
    const float* __restrict__ obs,
    const float* __restrict__ noise,
    const int*   __restrict__ tstep,
    float* __restrict__ np_out,
    float* __restrict__ w_out,
    float* __restrict__ sums)
{
    const int b     = blockIdx.x / C_BPB;
    const int chunk = blockIdx.x % C_BPB;
    const long base = (long)b * PF_N + (long)chunk * C_EPB;

    const float ob = obs[b];
    const float c  = 8.0f * cosf(1.2f * (float)(*tstep));

    float4 wreg[C_ITERS];
    float  lsum = 0.0f;

    #pragma unroll
    for (int i = 0; i < C_ITERS; ++i) {
        const long idx = base + (long)i * (TPB * 4) + (long)threadIdx.x * 4;
        const float4 x4  = *(const float4*)(particles + idx);
        const float4 n4  = *(const float4*)(noise + idx);
        const float4 wt4 = *(const float4*)(weights + idx);
        float4 xn, wv;
        compute4(x4, n4, wt4, ob, c, &xn, &wv, &lsum);
        nt_store4(np_out + idx, xn);   // never re-read: bypass caches
        wreg[i] = wv;
    }

    __shared__ float red[TPB / 64];
    __shared__ float s_inv;
    block_reduce_atomic(lsum, &sums[b], red);

    cg::this_grid().sync();

    if (threadIdx.x == 0)
        s_inv = 1.0f / atomicAdd(&sums[b], 0.0f);  // coherent device-scope read
    __syncthreads();
    const float inv = s_inv;

    #pragma unroll
    for (int i = 0; i < C_ITERS; ++i) {
        const long idx = base + (long)i * (TPB * 4) + (long)threadIdx.x * 4;
        float4 w4 = wreg[i];
        w4.x *= inv; w4.y *= inv; w4.z *= inv; w4.w *= inv;
        nt_store4(w_out + idx, w4);    // never re-read
    }
}

// ======================= fallback: two-pass =======================
__global__ __launch_bounds__(TPB) void pf_pass1(
    const float* __restrict__ particles,
    const float* __restrict__ weights,
    const float* __restrict__ obs,
    const float* __restrict__ noise,
    const int*   __restrict__ tstep,
    float* __restrict__ np_out,
    float* __restrict__ sums)
{
    const int b     = blockIdx.x / F_BPB;
    const int chunk = blockIdx.x % F_BPB;
    const long base = (long)b * PF_N + (long)chunk * F_EPB;

    const float ob = obs[b];
    const float c  = 8.0f * cosf(1.2f * (float)(*tstep));

    float lsum = 0.0f;
    #pragma unroll
    for (int k = 0; k < F_EPT / 4; ++k) {
        const long idx = base + (long)k * (TPB * 4) + (long)threadIdx.x * 4;
        const float4 x4  = *(const float4*)(particles + idx);
        const float4 n4  = *(const float4*)(noise + idx);
        const float4 wt4 = *(const float4*)(weights + idx);
        float4 xn, wv;
        compute4(x4, n4, wt4, ob, c, &xn, &wv, &lsum);
        *(float4*)(np_out + idx) = xn;   // normal store: keep L3-warm for pass 2
    }

    __shared__ float red[TPB / 64];
    block_reduce_atomic(lsum, &sums[b], red);
}

__global__ __launch_bounds__(TPB) void pf_pass2(
    const float* __restrict__ np_out,
    const float* __restrict__ weights,
    const float* __restrict__ obs,
    const float* __restrict__ sums,
    float* __restrict__ w_out)
{
    const int b     = blockIdx.x / F_BPB;
    const int chunk = blockIdx.x % F_BPB;
    const long base = (long)b * PF_N + (long)chunk * F_EPB;

    const float ob     = obs[b];
    const float inv    = 1.0f / sums[b];
    const float nhl2pi = -0.9189385f;

    #pragma unroll
    for (int k = 0; k < F_EPT / 4; ++k) {
        const long idx = base + (long)k * (TPB * 4) + (long)threadIdx.x * 4;
        const float4 x4  = *(const float4*)(np_out + idx);
        const float4 wt4 = *(const float4*)(weights + idx);
        float xs[4] = {x4.x, x4.y, x4.z, x4.w};
        float ws[4] = {wt4.x, wt4.y, wt4.z, wt4.w};
        float wn[4];
        #pragma unroll
        for (int j = 0; j < 4; ++j) {
            const float om = (xs[j] * xs[j]) * 0.05f;
            const float d  = ob - om;
            wn[j] = ws[j] * __expf(-0.5f * d * d + nhl2pi) * inv;
        }
        float4 w4; w4.x = wn[0]; w4.y = wn[1]; w4.z = wn[2]; w4.w = wn[3];
        nt_store4(w_out + idx, w4);
    }
}

extern "C" void kernel_launch(void* const* d_in, const int* in_sizes, int n_in,
                              void* d_out, int out_size, void* d_ws, size_t ws_size,
                              hipStream_t stream) {
    const float* particles = (const float*)d_in[0];
    const float* weights   = (const float*)d_in[1];
    const float* obs       = (const float*)d_in[2];
    const float* noise     = (const float*)d_in[3];
    // d_in[4] = uniforms: dead code (resample result unused by reference outputs)
    const int*   tstep     = (const int*)d_in[5];

    float* np_out = (float*)d_out;
    float* w_out  = (float*)d_out + (long)PF_B * PF_N;
    float* sums   = (float*)d_ws;

    (void)hipMemsetAsync(d_ws, 0, PF_B * sizeof(float), stream);

    void* args[] = {
        (void*)&particles, (void*)&weights, (void*)&obs, (void*)&noise,
        (void*)&tstep, (void*)&np_out, (void*)&w_out, (void*)&sums
    };
    hipError_t err = hipLaunchCooperativeKernel((const void*)pf_fused,
                                                dim3(C_NBLK), dim3(TPB),
                                                args, 0, stream);
    if (err != hipSuccess) {
        // deterministic fallback: two-pass, no grid sync
        pf_pass1<<<F_GRID, TPB, 0, stream>>>(particles, weights, obs, noise,
                                             tstep, np_out, sums);
        pf_pass2<<<F_GRID, TPB, 0, stream>>>(np_out, weights, obs, sums, w_out);
    }
}